// Round 1
// baseline (1311.134 us; speedup 1.0000x reference)
//
#include <hip/hip_runtime.h>
#include <math.h>

#define DIM 128
#define HID 256
#define MT 32           // rows per block-tile
#define NT 512          // threads per block (8 waves)
#define H_STRIDE 136    // bf16 elems; 272B row stride (16B-aligned, 2-way bank alias = free)
#define G_STRIDE 280    // bf16 elems; 560B row stride
#define D_STRIDE 132    // f32 elems

typedef __attribute__((ext_vector_type(8))) short bf16x8;
typedef __attribute__((ext_vector_type(4))) float f32x4;

__device__ __forceinline__ unsigned short f2bf(float f) {
    union { float f; unsigned int u; } v; v.f = f;
    unsigned int u = v.u;
    return (unsigned short)((u + 0x7fffu + ((u >> 16) & 1u)) >> 16);  // RNE
}

__device__ __forceinline__ f32x4 splat4(float v) { f32x4 r = {v, v, v, v}; return r; }

__global__ __launch_bounds__(NT) void trw_kernel(
    const float* __restrict__ x,
    const float* __restrict__ ln_w, const float* __restrict__ ln_b,
    const float* __restrict__ w1, const float* __restrict__ b1,
    const float* __restrict__ w2, const float* __restrict__ b2,
    const float* __restrict__ wg, const float* __restrict__ bg,
    const int* __restrict__ passes_p,
    float* __restrict__ out, int nrows)
{
    __shared__ __align__(16) unsigned short hBuf[MT * H_STRIDE];   // h, bf16
    __shared__ __align__(16) unsigned short gBuf[MT * G_STRIDE];   // gelu(t), bf16
    __shared__ __align__(16) unsigned short a2Buf[MT * G_STRIDE];  // [state | refined], bf16
    __shared__ __align__(16) float dBuf[MT * D_STRIDE];            // gate*refined, f32

    const int tid = threadIdx.x;
    const int w   = tid >> 6;   // wave 0..7
    const int l   = tid & 63;
    const int q   = l >> 4;     // quad 0..3
    const int c16 = l & 15;

    // elementwise ownership: thread owns row erow, cols [ecg, ecg+8)
    const int erow = tid >> 4;
    const int ecg  = (tid & 15) << 3;

    const int np = passes_p[0];

    // ---- preload weights into register B-fragments (bf16) ----
    // GEMM1: wave w owns output coltiles {2w, 2w+1} of w1 (128x256)
    bf16x8 w1f[2][4];
#pragma unroll
    for (int ct = 0; ct < 2; ++ct) {
        const int col = (2*w + ct)*16 + c16;
#pragma unroll
        for (int kk = 0; kk < 4; ++kk) {
            bf16x8 f;
#pragma unroll
            for (int j = 0; j < 8; ++j)
                f[j] = (short)f2bf(w1[(kk*32 + q*8 + j)*HID + col]);
            w1f[ct][kk] = f;
        }
    }
    // GEMM2/GEMM3: wave w owns output coltile w of w2 / wg (256x128)
    const int col2 = w*16 + c16;
    bf16x8 w2f[8], wgf[8];
#pragma unroll
    for (int kk = 0; kk < 8; ++kk) {
        bf16x8 f2, fg;
#pragma unroll
        for (int j = 0; j < 8; ++j) {
            const int k = kk*32 + q*8 + j;
            f2[j] = (short)f2bf(w2[k*DIM + col2]);
            fg[j] = (short)f2bf(wg[k*DIM + col2]);
        }
        w2f[kk] = f2;
        wgf[kk] = fg;
    }
    const float b1v0 = b1[(2*w + 0)*16 + c16];
    const float b1v1 = b1[(2*w + 1)*16 + c16];
    const float b2v  = b2[col2];
    const float bgv  = bg[col2];

    float lw[8], lb[8];
#pragma unroll
    for (int j = 0; j < 8; ++j) { lw[j] = ln_w[ecg + j]; lb[j] = ln_b[ecg + j]; }

    const int nTiles = nrows / MT;
    for (int tile = blockIdx.x; tile < nTiles; tile += gridDim.x) {
        float st[8];
        {
            const float* xr = x + (size_t)(tile*MT + erow)*DIM + ecg;
            f32x4 a = *(const f32x4*)xr;
            f32x4 b = *(const f32x4*)(xr + 4);
#pragma unroll
            for (int j = 0; j < 4; ++j) { st[j] = a[j]; st[4+j] = b[j]; }
        }

        for (int p = 0; p < np; ++p) {
            // ---- (a) LayerNorm (fp32, 16-lane shuffle reduce) ----
            float s1 = 0.f, s2 = 0.f;
#pragma unroll
            for (int j = 0; j < 8; ++j) { s1 += st[j]; s2 += st[j]*st[j]; }
#pragma unroll
            for (int m = 8; m >= 1; m >>= 1) {
                s1 += __shfl_xor(s1, m);
                s2 += __shfl_xor(s2, m);
            }
            const float mu = s1 * (1.f/DIM);
            const float rs = rsqrtf(s2*(1.f/DIM) - mu*mu + 1e-5f);
            bf16x8 hv, sv;
#pragma unroll
            for (int j = 0; j < 8; ++j) {
                hv[j] = (short)f2bf((st[j] - mu)*rs*lw[j] + lb[j]);
                sv[j] = (short)f2bf(st[j]);
            }
            *(bf16x8*)&hBuf[erow*H_STRIDE + ecg]  = hv;
            *(bf16x8*)&a2Buf[erow*G_STRIDE + ecg] = sv;  // state half of GEMM3's A
            __syncthreads();

            // ---- (c) GEMM1: t = h @ w1 + b1, then exact GELU -> gBuf ----
            f32x4 acc0[2], acc1[2];
#pragma unroll
            for (int rt = 0; rt < 2; ++rt) { acc0[rt] = splat4(b1v0); acc1[rt] = splat4(b1v1); }
#pragma unroll
            for (int rt = 0; rt < 2; ++rt)
#pragma unroll
                for (int kk = 0; kk < 4; ++kk) {
                    bf16x8 a = *(bf16x8*)&hBuf[(rt*16 + c16)*H_STRIDE + kk*32 + q*8];
                    acc0[rt] = __builtin_amdgcn_mfma_f32_16x16x32_bf16(a, w1f[0][kk], acc0[rt], 0, 0, 0);
                    acc1[rt] = __builtin_amdgcn_mfma_f32_16x16x32_bf16(a, w1f[1][kk], acc1[rt], 0, 0, 0);
                }
#pragma unroll
            for (int rt = 0; rt < 2; ++rt)
#pragma unroll
                for (int r = 0; r < 4; ++r) {
                    const int row = rt*16 + q*4 + r;
                    const float t0 = acc0[rt][r];
                    const float t1 = acc1[rt][r];
                    const float g0 = 0.5f*t0*(1.f + erff(t0*0.70710678f));
                    const float g1 = 0.5f*t1*(1.f + erff(t1*0.70710678f));
                    gBuf[row*G_STRIDE + (2*w + 0)*16 + c16] = f2bf(g0);
                    gBuf[row*G_STRIDE + (2*w + 1)*16 + c16] = f2bf(g1);
                }
            __syncthreads();

            // ---- (e) GEMM2: refined = g @ w2 + b2 (stays in regs); bf16 copy -> a2Buf ----
            f32x4 acc2[2];
            acc2[0] = splat4(b2v); acc2[1] = splat4(b2v);
#pragma unroll
            for (int rt = 0; rt < 2; ++rt)
#pragma unroll
                for (int kk = 0; kk < 8; ++kk) {
                    bf16x8 a = *(bf16x8*)&gBuf[(rt*16 + c16)*G_STRIDE + kk*32 + q*8];
                    acc2[rt] = __builtin_amdgcn_mfma_f32_16x16x32_bf16(a, w2f[kk], acc2[rt], 0, 0, 0);
                }
#pragma unroll
            for (int rt = 0; rt < 2; ++rt)
#pragma unroll
                for (int r = 0; r < 4; ++r) {
                    const int row = rt*16 + q*4 + r;
                    a2Buf[row*G_STRIDE + DIM + col2] = f2bf(acc2[rt][r]);
                }
            __syncthreads();

            // ---- (g) GEMM3: gatepre = [state|refined] @ wg + bg; delta = sigmoid * refined ----
            f32x4 acc3[2];
            acc3[0] = splat4(bgv); acc3[1] = splat4(bgv);
#pragma unroll
            for (int rt = 0; rt < 2; ++rt)
#pragma unroll
                for (int kk = 0; kk < 8; ++kk) {
                    bf16x8 a = *(bf16x8*)&a2Buf[(rt*16 + c16)*G_STRIDE + kk*32 + q*8];
                    acc3[rt] = __builtin_amdgcn_mfma_f32_16x16x32_bf16(a, wgf[kk], acc3[rt], 0, 0, 0);
                }
#pragma unroll
            for (int rt = 0; rt < 2; ++rt)
#pragma unroll
                for (int r = 0; r < 4; ++r) {
                    const int row = rt*16 + q*4 + r;
                    const float gate = 1.f/(1.f + expf(-acc3[rt][r]));
                    dBuf[row*D_STRIDE + col2] = gate * acc2[rt][r];  // same (row,col) tile as GEMM2
                }
            __syncthreads();

            // ---- (i) state += delta ----
#pragma unroll
            for (int j = 0; j < 8; ++j)
                st[j] += dBuf[erow*D_STRIDE + ecg + j];
            // no sync needed: dBuf next written at (g), behind 3 syncs
        }

        {
            float* orow = out + (size_t)(tile*MT + erow)*DIM + ecg;
            f32x4 a = {st[0], st[1], st[2], st[3]};
            f32x4 b = {st[4], st[5], st[6], st[7]};
            *(f32x4*)orow = a;
            *(f32x4*)(orow + 4) = b;
        }
    }
}

extern "C" void kernel_launch(void* const* d_in, const int* in_sizes, int n_in,
                              void* d_out, int out_size, void* d_ws, size_t ws_size,
                              hipStream_t stream) {
    const float* x    = (const float*)d_in[0];
    const float* ln_w = (const float*)d_in[1];
    const float* ln_b = (const float*)d_in[2];
    const float* w1   = (const float*)d_in[3];
    const float* b1   = (const float*)d_in[4];
    const float* w2   = (const float*)d_in[5];
    const float* b2   = (const float*)d_in[6];
    const float* wg   = (const float*)d_in[7];
    const float* bg   = (const float*)d_in[8];
    const int* passes = (const int*)d_in[9];
    float* out = (float*)d_out;

    const int nrows = in_sizes[0] / DIM;
    hipLaunchKernelGGL(trw_kernel, dim3(1024), dim3(NT), 0, stream,
                       x, ln_w, ln_b, w1, b1, w2, b2, wg, bg, passes, out, nrows);
}

// Round 2
// 1005.682 us; speedup vs baseline: 1.3037x; 1.3037x over previous
//
#include <hip/hip_runtime.h>
#include <math.h>

#define DIM 128
#define HID 256
#define MT 32           // rows per block-tile
#define NT 512          // threads per block (8 waves)
#define H_STRIDE 136    // bf16 elems (stride 68 dwords ≡ 4 mod 32 -> b128 reads at bank floor)
#define G_STRIDE 280    // bf16 elems, k-PERMUTED layout (see pi below)
#define R_STRIDE 136    // bf16 elems, refined buffer
#define D_STRIDE 132    // f32 elems, delta buffer (aliases gBuf storage)

typedef __attribute__((ext_vector_type(8))) short bf16x8;
typedef __attribute__((ext_vector_type(4))) float f32x4;
typedef __attribute__((ext_vector_type(4))) unsigned int u32x4;

// pack two f32 -> two bf16 in one dword, round-half-up-in-magnitude (bias add + byte perm)
__device__ __forceinline__ unsigned int pack2(float lo, float hi) {
    unsigned int a = __float_as_uint(lo) + 0x8000u;
    unsigned int b = __float_as_uint(hi) + 0x8000u;
    return __builtin_amdgcn_perm(b, a, 0x07060302u);  // [b.hi16 | a.hi16]
}
__device__ __forceinline__ unsigned short rb16(float f) {
    return (unsigned short)((__float_as_uint(f) + 0x8000u) >> 16);
}
__device__ __forceinline__ float frcp(float x) { return __builtin_amdgcn_rcpf(x); }
// tanh-form GELU: t * sigmoid(t*(A + B t^2)),  A=2c, B=2c*0.044715, c=sqrt(2/pi)
__device__ __forceinline__ float gelu_f(float t) {
    float m = (0.07135481283f * (t * t) + 1.5957691216f) * t;
    return t * frcp(1.f + __expf(-m));
}
__device__ __forceinline__ float sigm(float x) { return frcp(1.f + __expf(-x)); }
__device__ __forceinline__ f32x4 splat4(float v) { f32x4 r = {v, v, v, v}; return r; }

__global__ __launch_bounds__(NT) void trw_kernel(
    const float* __restrict__ x,
    const float* __restrict__ ln_w, const float* __restrict__ ln_b,
    const float* __restrict__ w1, const float* __restrict__ b1,
    const float* __restrict__ w2, const float* __restrict__ b2,
    const float* __restrict__ wg, const float* __restrict__ bg,
    const int* __restrict__ passes_p,
    float* __restrict__ out, int nrows)
{
    __shared__ __align__(16) unsigned short hBuf[MT * H_STRIDE];     // 8704 B
    __shared__ __align__(16) unsigned char  gdPool[MT * G_STRIDE * 2]; // 17920 B: gBuf(bf16) U dBuf(f32)
    __shared__ __align__(16) unsigned short rBuf[MT * R_STRIDE];     // 8704 B
    __shared__ __align__(16) float muB[MT];
    __shared__ __align__(16) float sgB[MT];
    unsigned short* gBuf   = (unsigned short*)gdPool;
    unsigned int*   gBuf32 = (unsigned int*)gdPool;
    float*          dBuf   = (float*)gdPool;   // 32*132*4 = 16896 <= 17920, lifetimes disjoint

    const int tid = threadIdx.x;
    const int w   = tid >> 6;   // wave 0..7
    const int l   = tid & 63;
    const int q   = l >> 4;     // quad 0..3
    const int c16 = l & 15;

    const int erow = tid >> 4;          // elementwise row
    const int ecg  = (tid & 15) << 3;   // elementwise col group (8 elems)

    const int np = passes_p[0];

    // ---- weight preload into register B-fragments ----
    // GEMM1: wave w owns coltiles {2w, 2w+1} of w1 (128x256)
    bf16x8 w1f[2][4];
#pragma unroll
    for (int ct = 0; ct < 2; ++ct) {
        const int col = (2*w + ct)*16 + c16;
#pragma unroll
        for (int kk = 0; kk < 4; ++kk) {
            bf16x8 f;
#pragma unroll
            for (int j = 0; j < 8; ++j)
                f[j] = (short)rb16(w1[(kk*32 + q*8 + j)*HID + col]);
            w1f[kk & 3][0] = w1f[kk & 3][0]; // no-op to appease nothing
            w1f[ct][kk] = f;
        }
    }
    // GEMM2: wave w owns coltile w of w2 (256x128); k-dim PERMUTED to match gBuf's packed layout:
    //   physical p (within 32-group) holds logical L = 16*(p&1) + (p>>1)
    const int col2 = w*16 + c16;
    bf16x8 w2f[8];
#pragma unroll
    for (int kk = 0; kk < 8; ++kk) {
        bf16x8 f2;
#pragma unroll
        for (int j = 0; j < 8; ++j) {
            const int p  = kk*32 + q*8 + j;
            const int p5 = p & 31;
            const int L  = (p & ~31) + ((p5 & 1) << 4) + (p5 >> 1);
            f2[j] = (short)rb16(w2[L*DIM + col2]);
        }
        w2f[kk] = f2;
    }
    // GEMM3 split: wg_s' = wg[:128]/ln_w (state half, fused into G1 via hBuf); wg_r = wg[128:]
    bf16x8 wgsf[4], wgrf[4];
#pragma unroll
    for (int kk = 0; kk < 4; ++kk) {
        bf16x8 fs, fr;
#pragma unroll
        for (int j = 0; j < 8; ++j) {
            const int k = kk*32 + q*8 + j;
            fs[j] = (short)rb16(wg[k*DIM + col2] / ln_w[k]);
            fr[j] = (short)rb16(wg[(128 + k)*DIM + col2]);
        }
        wgsf[kk] = fs; wgrf[kk] = fr;
    }
    // per-column constants for the algebraic state-half:
    //   state@wg_s = sg*(h@wg_s') + mu*cs1 - sg*cs2
    float cs1 = 0.f, cs2 = 0.f;
    for (int k = 0; k < 128; ++k) {
        const float wv = wg[k*DIM + col2];
        cs1 += wv;
        cs2 += ln_b[k] * wv / ln_w[k];
    }
    const float b1v0 = b1[(2*w + 0)*16 + c16];
    const float b1v1 = b1[(2*w + 1)*16 + c16];
    const float b2v  = b2[col2];
    const float bgv  = bg[col2];

    float lw[8], lb[8];
#pragma unroll
    for (int j = 0; j < 8; ++j) { lw[j] = ln_w[ecg + j]; lb[j] = ln_b[ecg + j]; }

    const int nTiles = nrows / MT;
    for (int tile = blockIdx.x; tile < nTiles; tile += gridDim.x) {
        float st[8];
        {
            const float* xr = x + (size_t)(tile*MT + erow)*DIM + ecg;
            f32x4 a = *(const f32x4*)xr;
            f32x4 b = *(const f32x4*)(xr + 4);
#pragma unroll
            for (int j = 0; j < 4; ++j) { st[j] = a[j]; st[4+j] = b[j]; }
        }

        for (int p = 0; p < np; ++p) {
            // ---- (a) LayerNorm ----
            float s1 = 0.f, s2 = 0.f;
#pragma unroll
            for (int j = 0; j < 8; ++j) { s1 += st[j]; s2 += st[j]*st[j]; }
#pragma unroll
            for (int m = 8; m >= 1; m >>= 1) {
                s1 += __shfl_xor(s1, m);
                s2 += __shfl_xor(s2, m);
            }
            const float mu = s1 * (1.f/DIM);
            const float ve = s2*(1.f/DIM) - mu*mu + 1e-5f;
            const float rs = rsqrtf(ve);
            const float sg = ve * rs;            // sqrt(var+eps)
            float h[8];
#pragma unroll
            for (int j = 0; j < 8; ++j) {
                const float A = rs * lw[j];
                h[j] = fmaf(st[j], A, fmaf(-mu, A, lb[j]));
            }
            u32x4 hv = { pack2(h[0],h[1]), pack2(h[2],h[3]), pack2(h[4],h[5]), pack2(h[6],h[7]) };
            *(u32x4*)&hBuf[erow*H_STRIDE + ecg] = hv;
            if ((tid & 15) == 0) { muB[erow] = mu; sgB[erow] = sg; }
            __syncthreads();

            // ---- (b) GEMM1 (w1) + state-half of gate (wg_s') sharing hBuf A-frags ----
            f32x4 acc0[2], acc1[2], acc3[2];
#pragma unroll
            for (int rt = 0; rt < 2; ++rt) {
                acc0[rt] = splat4(b1v0); acc1[rt] = splat4(b1v1); acc3[rt] = splat4(0.f);
            }
#pragma unroll
            for (int rt = 0; rt < 2; ++rt)
#pragma unroll
                for (int kk = 0; kk < 4; ++kk) {
                    bf16x8 a = *(bf16x8*)&hBuf[(rt*16 + c16)*H_STRIDE + kk*32 + q*8];
                    acc0[rt] = __builtin_amdgcn_mfma_f32_16x16x32_bf16(a, w1f[0][kk], acc0[rt], 0, 0, 0);
                    acc1[rt] = __builtin_amdgcn_mfma_f32_16x16x32_bf16(a, w1f[1][kk], acc1[rt], 0, 0, 0);
                    acc3[rt] = __builtin_amdgcn_mfma_f32_16x16x32_bf16(a, wgsf[kk],  acc3[rt], 0, 0, 0);
                }
            // GELU epilogue -> packed b32 writes into k-permuted gBuf (conflict-free)
#pragma unroll
            for (int rt = 0; rt < 2; ++rt)
#pragma unroll
                for (int r = 0; r < 4; ++r) {
                    const int row = rt*16 + q*4 + r;
                    const float g0 = gelu_f(acc0[rt][r]);
                    const float g1 = gelu_f(acc1[rt][r]);
                    gBuf32[row*(G_STRIDE/2) + 16*w + c16] = pack2(g0, g1);
                }
            __syncthreads();

            // ---- (c) prescale acc3 with per-row stats, then GEMM2 (refined) ----
#pragma unroll
            for (int rt = 0; rt < 2; ++rt) {
                f32x4 muv = *(f32x4*)&muB[rt*16 + q*4];
                f32x4 sgv = *(f32x4*)&sgB[rt*16 + q*4];
#pragma unroll
                for (int r = 0; r < 4; ++r) {
                    float t = fmaf(muv[r], cs1, bgv);
                    t = fmaf(-sgv[r], cs2, t);
                    acc3[rt][r] = fmaf(sgv[r], acc3[rt][r], t);
                }
            }
            f32x4 acc2[2];
            acc2[0] = splat4(b2v); acc2[1] = splat4(b2v);
#pragma unroll
            for (int rt = 0; rt < 2; ++rt)
#pragma unroll
                for (int kk = 0; kk < 8; ++kk) {
                    bf16x8 a = *(bf16x8*)&gBuf[(rt*16 + c16)*G_STRIDE + kk*32 + q*8];
                    acc2[rt] = __builtin_amdgcn_mfma_f32_16x16x32_bf16(a, w2f[kk], acc2[rt], 0, 0, 0);
                }
#pragma unroll
            for (int rt = 0; rt < 2; ++rt)
#pragma unroll
                for (int r = 0; r < 4; ++r) {
                    const int row = rt*16 + q*4 + r;
                    rBuf[row*R_STRIDE + col2] = rb16(acc2[rt][r]);
                }
            __syncthreads();

            // ---- (d) refined-half of gate (wg_r), sigmoid, delta -> dBuf ----
#pragma unroll
            for (int rt = 0; rt < 2; ++rt)
#pragma unroll
                for (int kk = 0; kk < 4; ++kk) {
                    bf16x8 a = *(bf16x8*)&rBuf[(rt*16 + c16)*R_STRIDE + kk*32 + q*8];
                    acc3[rt] = __builtin_amdgcn_mfma_f32_16x16x32_bf16(a, wgrf[kk], acc3[rt], 0, 0, 0);
                }
#pragma unroll
            for (int rt = 0; rt < 2; ++rt)
#pragma unroll
                for (int r = 0; r < 4; ++r) {
                    const int row = rt*16 + q*4 + r;
                    dBuf[row*D_STRIDE + col2] = sigm(acc3[rt][r]) * acc2[rt][r];
                }
            __syncthreads();

            // ---- (e) state += delta ----
            {
                f32x4 d0 = *(f32x4*)&dBuf[erow*D_STRIDE + ecg];
                f32x4 d1 = *(f32x4*)&dBuf[erow*D_STRIDE + ecg + 4];
#pragma unroll
                for (int j = 0; j < 4; ++j) { st[j] += d0[j]; st[4+j] += d1[j]; }
            }
            // no sync needed: dBuf next written at (d), behind syncs (a),(b),(c)
        }

        {
            float* orow = out + (size_t)(tile*MT + erow)*DIM + ecg;
            f32x4 a = {st[0], st[1], st[2], st[3]};
            f32x4 b = {st[4], st[5], st[6], st[7]};
            *(f32x4*)orow = a;
            *(f32x4*)(orow + 4) = b;
        }
    }
}

extern "C" void kernel_launch(void* const* d_in, const int* in_sizes, int n_in,
                              void* d_out, int out_size, void* d_ws, size_t ws_size,
                              hipStream_t stream) {
    const float* x    = (const float*)d_in[0];
    const float* ln_w = (const float*)d_in[1];
    const float* ln_b = (const float*)d_in[2];
    const float* w1   = (const float*)d_in[3];
    const float* b1   = (const float*)d_in[4];
    const float* w2   = (const float*)d_in[5];
    const float* b2   = (const float*)d_in[6];
    const float* wg   = (const float*)d_in[7];
    const float* bg   = (const float*)d_in[8];
    const int* passes = (const int*)d_in[9];
    float* out = (float*)d_out;

    const int nrows = in_sizes[0] / DIM;
    hipLaunchKernelGGL(trw_kernel, dim3(1024), dim3(NT), 0, stream,
                       x, ln_w, ln_b, w1, b1, w2, b2, wg, bg, passes, out, nrows);
}

// Round 3
// 958.795 us; speedup vs baseline: 1.3675x; 1.0489x over previous
//
#include <hip/hip_runtime.h>
#include <math.h>

#define DIM 128
#define HID 256
#define MT 64           // rows per block-tile
#define NT 512          // threads per block (8 waves)
#define H_STRIDE 136    // bf16 elems (68 dw ≡ 4 mod 32)
#define G_STRIDE 264    // bf16 elems (132 dw ≡ 4 mod 32), k-permuted packed layout
#define D_STRIDE 132    // f32 elems (132 dw ≡ 4 mod 32; write pattern is 2-way = free)

typedef __attribute__((ext_vector_type(8))) short bf16x8;
typedef __attribute__((ext_vector_type(4))) float f32x4;
typedef __attribute__((ext_vector_type(4))) unsigned int u32x4;

#define MFMA(a, b, c) __builtin_amdgcn_mfma_f32_16x16x32_bf16((a), (b), (c), 0, 0, 0)

__device__ __forceinline__ unsigned int pack2(float lo, float hi) {
    unsigned int a = __float_as_uint(lo) + 0x8000u;
    unsigned int b = __float_as_uint(hi) + 0x8000u;
    return __builtin_amdgcn_perm(b, a, 0x07060302u);  // [b.hi16 | a.hi16]
}
__device__ __forceinline__ unsigned short rb16(float f) {
    return (unsigned short)((__float_as_uint(f) + 0x8000u) >> 16);
}
__device__ __forceinline__ float frcp(float x) { return __builtin_amdgcn_rcpf(x); }
__device__ __forceinline__ float ex2(float x)  { return __builtin_amdgcn_exp2f(x); }
// tanh-form GELU, exp folded to exp2: g = t * 1/(1+2^(t*(A + B t^2)))
__device__ __forceinline__ float gelu_f(float t) {
    const float u = t * fmaf(t * t, -0.1029436f, -2.3022082f);
    return t * frcp(1.f + ex2(u));
}
__device__ __forceinline__ float sigm(float x) { return frcp(1.f + ex2(-1.442695f * x)); }
__device__ __forceinline__ f32x4 splat4(float v) { f32x4 r = {v, v, v, v}; return r; }

// ---- setup: w2g = w2 @ wg_r (256x128 @ 128x128) -> ws fp32; row 256 = bg + b2 @ wg_r ----
__global__ void w2g_setup(const float* __restrict__ w2, const float* __restrict__ wg,
                          const float* __restrict__ b2, const float* __restrict__ bg,
                          float* __restrict__ w2g)
{
    __shared__ float wr[DIM][DIM + 1];
    const int t = threadIdx.x;  // 256
    for (int i = t; i < DIM * DIM; i += 256)
        wr[i >> 7][i & 127] = wg[DIM * DIM + i];  // wg_r = wg[128:,:]
    __syncthreads();
    const int row = blockIdx.x * 32 + (t >> 3);  // 8 blocks x 32 rows
    const int c0  = (t & 7) * 16;
    float acc[16];
#pragma unroll
    for (int j = 0; j < 16; ++j) acc[j] = 0.f;
    for (int k = 0; k < DIM; ++k) {
        const float a = w2[row * DIM + k];
#pragma unroll
        for (int j = 0; j < 16; ++j) acc[j] = fmaf(a, wr[k][c0 + j], acc[j]);
    }
#pragma unroll
    for (int j = 0; j < 16; ++j) w2g[row * DIM + c0 + j] = acc[j];
    if (blockIdx.x == 0 && t < DIM) {
        float s = bg[t];
        for (int k = 0; k < DIM; ++k) s = fmaf(b2[k], wr[k][t], s);
        w2g[256 * DIM + t] = s;
    }
}

__global__ __launch_bounds__(NT) void trw_kernel(
    const float* __restrict__ x,
    const float* __restrict__ ln_w, const float* __restrict__ ln_b,
    const float* __restrict__ w1, const float* __restrict__ b1,
    const float* __restrict__ w2, const float* __restrict__ b2,
    const float* __restrict__ wg,
    const float* __restrict__ w2g,
    const int* __restrict__ passes_p,
    float* __restrict__ out, int nrows)
{
    __shared__ __align__(16) unsigned short hBuf[MT * H_STRIDE];  // 17408 B
    __shared__ __align__(16) unsigned short gBuf[MT * G_STRIDE];  // 33792 B
    __shared__ __align__(16) float dBuf[MT * D_STRIDE];           // 33792 B
    __shared__ __align__(16) float muB[MT];
    __shared__ __align__(16) float sgB[MT];
    unsigned int* gBuf32 = (unsigned int*)gBuf;

    const int tid = threadIdx.x;
    const int w = tid >> 6, l = tid & 63, q = l >> 4, c16 = l & 15;
    const int hrow = tid >> 3;          // hub: 64 rows, 8 threads/row
    const int hcg  = (tid & 7) << 4;    // hub: 16 cols/thread
    const int np = passes_p[0];

    // ---- stage-1 B-frags: w1' = lw∘w1 coltiles {2w,2w+1}; wg_s coltile {w} ----
    const int colA = 32 * w + c16, colB = colA + 16, colG = 16 * w + c16;
    bf16x8 w1f[2][4], wgsf[4];
#pragma unroll
    for (int kk = 0; kk < 4; ++kk) {
        bf16x8 fa, fb, fg;
#pragma unroll
        for (int j = 0; j < 8; ++j) {
            const int k = kk * 32 + q * 8 + j;
            const float lwk = ln_w[k];
            fa[j] = (short)rb16(lwk * w1[k * HID + colA]);
            fb[j] = (short)rb16(lwk * w1[k * HID + colB]);
            fg[j] = (short)rb16(wg[k * DIM + colG]);
        }
        w1f[0][kk] = fa; w1f[1][kk] = fb; wgsf[kk] = fg;
    }
    // ---- stage-2 B-frags (k-permuted to match gBuf packing): w2 and w2g, coltile {w} ----
    bf16x8 w2f[8], w2gf[8];
#pragma unroll
    for (int kk = 0; kk < 8; ++kk) {
        bf16x8 f2, fg;
#pragma unroll
        for (int j = 0; j < 8; ++j) {
            const int p  = kk * 32 + q * 8 + j;
            const int p5 = p & 31;
            const int L  = (p & ~31) + ((p5 & 1) << 4) + (p5 >> 1);
            f2[j] = (short)rb16(w2[L * DIM + colG]);
            fg[j] = (short)rb16(w2g[L * DIM + colG]);
        }
        w2f[kk] = f2; w2gf[kk] = fg;
    }
    // biases: b1' = b1 + lb@w1 ; cs1 = sum_k wg_s[k][colG] ; bgv = bg + b2@wg_r
    float b1vA = b1[colA], b1vB = b1[colB], cs1 = 0.f;
    for (int k = 0; k < DIM; ++k) {
        const float lbk = ln_b[k];
        b1vA = fmaf(lbk, w1[k * HID + colA], b1vA);
        b1vB = fmaf(lbk, w1[k * HID + colB], b1vB);
        cs1 += wg[k * DIM + colG];
    }
    const float b2v = b2[colG];
    const float bgv = w2g[256 * DIM + colG];

    const int nTiles = nrows / MT;
    for (int tile = blockIdx.x; tile < nTiles; tile += gridDim.x) {
        float st[16];
        {
            const float* xr = x + (size_t)(tile * MT + hrow) * DIM + hcg;
#pragma unroll
            for (int v = 0; v < 4; ++v) {
                f32x4 a = *(const f32x4*)(xr + 4 * v);
#pragma unroll
                for (int j = 0; j < 4; ++j) st[4 * v + j] = a[j];
            }
        }

        for (int p = 0; p < np; ++p) {
            // ---- hub: state += delta (p>0), LN -> h' = (st-mu)*rs ----
            if (p > 0) {
#pragma unroll
                for (int v = 0; v < 4; ++v) {
                    f32x4 d = *(f32x4*)&dBuf[hrow * D_STRIDE + hcg + 4 * v];
#pragma unroll
                    for (int j = 0; j < 4; ++j) st[4 * v + j] += d[j];
                }
            }
            float s1 = 0.f, s2 = 0.f;
#pragma unroll
            for (int j = 0; j < 16; ++j) { s1 += st[j]; s2 = fmaf(st[j], st[j], s2); }
#pragma unroll
            for (int m = 4; m >= 1; m >>= 1) { s1 += __shfl_xor(s1, m); s2 += __shfl_xor(s2, m); }
            const float mu = s1 * (1.f / DIM);
            const float ve = fmaf(-mu, mu, s2 * (1.f / DIM)) + 1e-5f;
            const float rs = rsqrtf(ve);
            const float sg = ve * rs;
            const float mrs = mu * rs;
            unsigned int hp[8];
#pragma unroll
            for (int j = 0; j < 8; ++j)
                hp[j] = pack2(fmaf(st[2 * j], rs, -mrs), fmaf(st[2 * j + 1], rs, -mrs));
            u32x4 h0 = {hp[0], hp[1], hp[2], hp[3]}, h1 = {hp[4], hp[5], hp[6], hp[7]};
            *(u32x4*)&hBuf[hrow * H_STRIDE + hcg]     = h0;
            *(u32x4*)&hBuf[hrow * H_STRIDE + hcg + 8] = h1;
            if ((tid & 7) == 0) { muB[hrow] = mu; sgB[hrow] = sg; }
            __syncthreads();

            // ---- stage 1: [t0 t1 | gs] = h' @ [w1' | wg_s], K=128 ----
            f32x4 acc0[4], acc1[4], accg[4];
#pragma unroll
            for (int rt = 0; rt < 4; ++rt) {
                acc0[rt] = splat4(b1vA); acc1[rt] = splat4(b1vB); accg[rt] = splat4(0.f);
            }
#pragma unroll
            for (int rt = 0; rt < 4; ++rt)
#pragma unroll
                for (int kk = 0; kk < 4; ++kk) {
                    bf16x8 a = *(bf16x8*)&hBuf[(rt * 16 + c16) * H_STRIDE + kk * 32 + q * 8];
                    acc0[rt] = MFMA(a, w1f[0][kk], acc0[rt]);
                    acc1[rt] = MFMA(a, w1f[1][kk], acc1[rt]);
                    accg[rt] = MFMA(a, wgsf[kk], accg[rt]);
                }
            // epilogue: gelu -> packed gBuf; rescale gs with per-row stats
#pragma unroll
            for (int rt = 0; rt < 4; ++rt) {
                f32x4 muv = *(f32x4*)&muB[rt * 16 + q * 4];
                f32x4 sgv = *(f32x4*)&sgB[rt * 16 + q * 4];
#pragma unroll
                for (int r = 0; r < 4; ++r) {
                    const int row = rt * 16 + q * 4 + r;
                    gBuf32[row * (G_STRIDE / 2) + 16 * w + c16] =
                        pack2(gelu_f(acc0[rt][r]), gelu_f(acc1[rt][r]));
                    accg[rt][r] = fmaf(sgv[r], accg[rt][r], muv[r] * cs1);
                }
            }
            __syncthreads();

            // ---- stage 2: [refined | gr] = g @ [w2 | w2g], K=256 ----
            f32x4 acc2[4], accr[4];
#pragma unroll
            for (int rt = 0; rt < 4; ++rt) { acc2[rt] = splat4(b2v); accr[rt] = splat4(bgv); }
#pragma unroll
            for (int rt = 0; rt < 4; ++rt)
#pragma unroll
                for (int kk = 0; kk < 8; ++kk) {
                    bf16x8 a = *(bf16x8*)&gBuf[(rt * 16 + c16) * G_STRIDE + kk * 32 + q * 8];
                    acc2[rt] = MFMA(a, w2f[kk], acc2[rt]);
                    accr[rt] = MFMA(a, w2gf[kk], accr[rt]);
                }
            // epilogue: gate = sigm(gs + gr); delta = gate * refined -> dBuf
#pragma unroll
            for (int rt = 0; rt < 4; ++rt)
#pragma unroll
                for (int r = 0; r < 4; ++r) {
                    const int row = rt * 16 + q * 4 + r;
                    const float gate = sigm(accg[rt][r] + accr[rt][r]);
                    dBuf[row * D_STRIDE + 16 * w + c16] = gate * acc2[rt][r];
                }
            __syncthreads();
        }

        // final state += delta; store
        {
            float* orow = out + (size_t)(tile * MT + hrow) * DIM + hcg;
#pragma unroll
            for (int v = 0; v < 4; ++v) {
                f32x4 d = *(f32x4*)&dBuf[hrow * D_STRIDE + hcg + 4 * v];
                f32x4 o;
#pragma unroll
                for (int j = 0; j < 4; ++j) o[j] = st[4 * v + j] + d[j];
                *(f32x4*)(orow + 4 * v) = o;
            }
        }
    }
}

extern "C" void kernel_launch(void* const* d_in, const int* in_sizes, int n_in,
                              void* d_out, int out_size, void* d_ws, size_t ws_size,
                              hipStream_t stream) {
    const float* x    = (const float*)d_in[0];
    const float* ln_w = (const float*)d_in[1];
    const float* ln_b = (const float*)d_in[2];
    const float* w1   = (const float*)d_in[3];
    const float* b1   = (const float*)d_in[4];
    const float* w2   = (const float*)d_in[5];
    const float* b2   = (const float*)d_in[6];
    const float* wg   = (const float*)d_in[7];
    const float* bg   = (const float*)d_in[8];
    const int* passes = (const int*)d_in[9];
    float* out = (float*)d_out;
    float* w2g = (float*)d_ws;  // 257*128 fp32 = 131584 B

    const int nrows = in_sizes[0] / DIM;
    hipLaunchKernelGGL(w2g_setup, dim3(8), dim3(256), 0, stream, w2, wg, b2, bg, w2g);
    hipLaunchKernelGGL(trw_kernel, dim3(1024), dim3(NT), 0, stream,
                       x, ln_w, ln_b, w1, b1, w2, b2, wg, w2g, passes, out, nrows);
}